// Round 6
// baseline (126.398 us; speedup 1.0000x reference)
//
#include <hip/hip_runtime.h>
#include <hip/hip_bf16.h>

// Problem constants (fixed by setup_inputs)
constexpr int B_   = 4;
constexpr int C_   = 256;
constexpr int HF   = 16;
constexpr int WF   = 16;
constexpr int HH   = 512;
constexpr int WW   = 512;
constexpr int NSEG = 1024;
constexpr int FOUT = 192;
constexpr int NCELL = HF * WF;      // 256
constexpr int NPIX  = B_ * HH * WW; // 1048576
constexpr int NBINS = B_ * NSEG;    // 4096
constexpr int SB    = 512;          // scatter blocks
constexpr int PPB   = NPIX / SB;    // 2048 pixels per block
constexpr int BPI   = SB / B_;      // 128 blocks per image
constexpr int CAP   = 384;          // per-bin slot capacity (max Poisson(256) over 4096 bins ~ 320)
constexpr int GPB   = 48;           // gemm_P blocks fused into k_scat

// -----------------------------------------------------------------------------
// gemm_P (256-thread body): P[b][ij][f] = sum_c feat[b][c][ij] * w[f][c]
// M=64-tile of ij, N=64-tile of f, K=256. 4x4 outputs per thread.
// -----------------------------------------------------------------------------
struct PS { float Fs[32][65]; float Ws[64][33]; };

__device__ void gemm_P_body(int gp, const float* __restrict__ feat,
                            const float* __restrict__ w, float* __restrict__ P) {
    __shared__ PS sm;
    int ni = gp % 3;
    int mi = (gp / 3) & 3;
    int b  = gp / 12;
    const float* Fb = feat + (size_t)b * C_ * NCELL;

    int tid = threadIdx.x;
    int tx = tid & 15, ty = tid >> 4;
    float acc[4][4] = {};

    for (int k0 = 0; k0 < C_; k0 += 32) {
        #pragma unroll
        for (int l = 0; l < 2; ++l) {
            int li = tid * 2 + l;            // 0..511
            int kk = li >> 4;                // 0..31
            int m4 = (li & 15) * 4;
            float4 vf = *reinterpret_cast<const float4*>(&Fb[(size_t)(k0 + kk) * NCELL + mi * 64 + m4]);
            sm.Fs[kk][m4 + 0] = vf.x; sm.Fs[kk][m4 + 1] = vf.y;
            sm.Fs[kk][m4 + 2] = vf.z; sm.Fs[kk][m4 + 3] = vf.w;
            int row = li >> 3;               // 0..63
            int kq  = (li & 7) * 4;
            float4 vw = *reinterpret_cast<const float4*>(&w[(size_t)(ni * 64 + row) * C_ + k0 + kq]);
            sm.Ws[row][kq + 0] = vw.x; sm.Ws[row][kq + 1] = vw.y;
            sm.Ws[row][kq + 2] = vw.z; sm.Ws[row][kq + 3] = vw.w;
        }
        __syncthreads();
        #pragma unroll
        for (int kk = 0; kk < 32; ++kk) {
            float ar[4], wr[4];
            #pragma unroll
            for (int i = 0; i < 4; ++i) ar[i] = sm.Fs[kk][ty * 4 + i];
            #pragma unroll
            for (int j = 0; j < 4; ++j) wr[j] = sm.Ws[tx * 4 + j][kk];
            #pragma unroll
            for (int i = 0; i < 4; ++i)
                #pragma unroll
                for (int j = 0; j < 4; ++j) acc[i][j] += ar[i] * wr[j];
        }
        __syncthreads();
    }

    #pragma unroll
    for (int i = 0; i < 4; ++i)
        #pragma unroll
        for (int j = 0; j < 4; ++j)
            P[(size_t)b * NCELL * FOUT + (size_t)(mi * 64 + ty * 4 + i) * FOUT + ni * 64 + tx * 4 + j] = acc[i][j];
}

// -----------------------------------------------------------------------------
// Pass 1: blocks [0,512): direct per-pixel rank reservation via L2-resident
// u32 atomics on cursor[4096]; store pixel coord straight into its bin slot.
// Zero LDS, zero barriers in this path -> max occupancy, pure MLP.
//         blocks [512,560): gemm_P (independent, overlaps).
// -----------------------------------------------------------------------------
__global__ __launch_bounds__(256) void k_scat(const int* __restrict__ seg,
                                              float* __restrict__ segout,
                                              unsigned* __restrict__ cursor,
                                              int* __restrict__ sorted,
                                              const float* __restrict__ feat,
                                              const float* __restrict__ w,
                                              float* __restrict__ P) {
    int blk = blockIdx.x;
    if (blk >= SB) { gemm_P_body(blk - SB, feat, w, P); return; }

    int tid = threadIdx.x;
    int b   = blk / BPI;

    size_t p0 = (size_t)blk * PPB;
    const int4* segv = reinterpret_cast<const int4*>(seg + p0);
    float4* outv = reinterpret_cast<float4*>(segout + p0);
    #pragma unroll
    for (int i = 0; i < 2; ++i) {
        int4 v = segv[i * 256 + tid];
        outv[i * 256 + tid] = make_float4((float)v.x, (float)v.y,
                                          (float)v.z, (float)v.w);
        unsigned pb = (unsigned)((p0 + (size_t)(i * 256 + tid) * 4) & (HH * WW - 1));
        int ss[4] = { v.x, v.y, v.z, v.w };
        #pragma unroll
        for (int c = 0; c < 4; ++c) {
            unsigned g = (unsigned)(b * NSEG + ss[c]);
            unsigned rank = atomicAdd(&cursor[g], 1u);
            if (rank < CAP) sorted[(size_t)g * CAP + rank] = (int)(pb + c);
        }
    }
}

// -----------------------------------------------------------------------------
// Pass 2: one 64-thread block per bin. Each lane loads int4 (4 pixels) so a
// typical bin (n~256) needs ONE load round; 16 LDS atomics/lane; reduce+store.
// -----------------------------------------------------------------------------
__device__ __forceinline__ void px_accum(float* acc, int p) {
    int y = p >> 9, x = p & (WW - 1);
    float sy = (y + 0.5f) * (1.0f / 32.0f) - 0.5f;
    float sx = (x + 0.5f) * (1.0f / 32.0f) - 0.5f;
    float fy = floorf(sy), fx = floorf(sx);
    int iy = (int)fy, ix = (int)fx;
    float wy1 = sy - fy, wy0 = 1.0f - wy1;
    float wx1 = sx - fx, wx0 = 1.0f - wx1;
    int y0 = max(iy, 0),          x0 = max(ix, 0);
    int y1 = min(iy + 1, HF - 1), x1 = min(ix + 1, WF - 1);
    atomicAdd(&acc[y0 * WF + x0], wy0 * wx0);
    atomicAdd(&acc[y0 * WF + x1], wy0 * wx1);
    atomicAdd(&acc[y1 * WF + x0], wy1 * wx0);
    atomicAdd(&acc[y1 * WF + x1], wy1 * wx1);
}

__global__ __launch_bounds__(64) void k_accum(const int* __restrict__ sorted,
                                              const unsigned* __restrict__ cursor,
                                              float* __restrict__ A) {
    __shared__ float acc[NCELL];
    int lane = threadIdx.x;
    int g = blockIdx.x;
    #pragma unroll
    for (int i = 0; i < 4; ++i) acc[lane + i * 64] = 0.0f;

    unsigned n = cursor[g]; if (n > CAP) n = CAP;
    int nI = (int)n;
    const int4* src4 = reinterpret_cast<const int4*>(sorted + (size_t)g * CAP);
    __syncthreads();

    for (int idx = lane; idx * 4 < nI; idx += 64) {
        int4 pv = src4[idx];
        int rem = nI - idx * 4;
        px_accum(acc, pv.x);
        if (rem > 1) px_accum(acc, pv.y);
        if (rem > 2) px_accum(acc, pv.z);
        if (rem > 3) px_accum(acc, pv.w);
    }
    __syncthreads();

    float rinv = 1.0f / fmaxf((float)nI, 1.0f);
    #pragma unroll
    for (int i = 0; i < 4; ++i)
        A[(size_t)g * NCELL + lane + i * 64] = acc[lane + i * 64] * rinv;
}

// -----------------------------------------------------------------------------
// Pass 3: out[g][f] = sum_ij A[g][ij] * P[b][ij][f] + bias[f]
// M=4096 N=192 K=256. A is NT (K-contig); P is T (K-major for N).
// -----------------------------------------------------------------------------
__global__ __launch_bounds__(256) void k_gemm_out(const float* __restrict__ A,
                                                  const float* __restrict__ P,
                                                  const float* __restrict__ bias,
                                                  float* __restrict__ out) {
    int ft = blockIdx.x % 3;     // 0..2
    int st = blockIdx.x / 3;     // 0..63
    int b  = st >> 4;            // 16 seg-tiles per image

    const float* Ab = A + (size_t)st * 64 * NCELL;
    const float* Pb = P + (size_t)b * NCELL * FOUT;

    __shared__ float As[64][33];
    __shared__ float Ps[32][65];

    int tid = threadIdx.x;
    int tx = tid & 15, ty = tid >> 4;
    float acc[4][4] = {};

    for (int k0 = 0; k0 < NCELL; k0 += 32) {
        #pragma unroll
        for (int l = 0; l < 2; ++l) {
            int li = tid * 2 + l;
            int row = li >> 3;
            int kq  = (li & 7) * 4;
            float4 va = *reinterpret_cast<const float4*>(&Ab[(size_t)row * NCELL + k0 + kq]);
            As[row][kq + 0] = va.x; As[row][kq + 1] = va.y;
            As[row][kq + 2] = va.z; As[row][kq + 3] = va.w;
            int kk = li >> 4;
            int n4 = (li & 15) * 4;
            float4 vp = *reinterpret_cast<const float4*>(&Pb[(size_t)(k0 + kk) * FOUT + ft * 64 + n4]);
            Ps[kk][n4 + 0] = vp.x; Ps[kk][n4 + 1] = vp.y;
            Ps[kk][n4 + 2] = vp.z; Ps[kk][n4 + 3] = vp.w;
        }
        __syncthreads();
        #pragma unroll
        for (int kk = 0; kk < 32; ++kk) {
            float mr[4], wr[4];
            #pragma unroll
            for (int i = 0; i < 4; ++i) mr[i] = As[ty * 4 + i][kk];
            #pragma unroll
            for (int j = 0; j < 4; ++j) wr[j] = Ps[kk][tx * 4 + j];
            #pragma unroll
            for (int i = 0; i < 4; ++i)
                #pragma unroll
                for (int j = 0; j < 4; ++j) acc[i][j] += mr[i] * wr[j];
        }
        __syncthreads();
    }

    #pragma unroll
    for (int i = 0; i < 4; ++i) {
        int row = st * 64 + ty * 4 + i;
        #pragma unroll
        for (int j = 0; j < 4; ++j) {
            int f = ft * 64 + tx * 4 + j;
            out[(size_t)row * FOUT + f] = acc[i][j] + bias[f];
        }
    }
}

extern "C" void kernel_launch(void* const* d_in, const int* in_sizes, int n_in,
                              void* d_out, int out_size, void* d_ws, size_t ws_size,
                              hipStream_t stream) {
    const float* feat = (const float*)d_in[0];   // (4,256,16,16)
    const float* w    = (const float*)d_in[1];   // (192,256)
    const float* bias = (const float*)d_in[2];   // (192,)
    const int*   seg  = (const int*)d_in[3];     // (4,512,512)

    float* out    = (float*)d_out;                          // (4,1024,192)
    float* segout = out + (size_t)B_ * NSEG * FOUT;         // (4,512,512) as float

    // Workspace layout:
    char* wsb = (char*)d_ws;
    unsigned* cursor = (unsigned*)wsb;                      // 4096 u32 = 16 KB
    int*      sorted = (int*)(wsb + (1u << 16));            // 4096*384 i32 ~ 6.3 MB
    float*    A      = (float*)(wsb + (8u << 20));          // 4096*256 f32 = 4 MB
    float*    P      = (float*)(wsb + (13u << 20));         // 4*256*192 f32

    hipMemsetAsync(cursor, 0, NBINS * sizeof(unsigned), stream);
    k_scat    <<<SB + GPB, 256, 0, stream>>>(seg, segout, cursor, sorted, feat, w, P);
    k_accum   <<<NBINS, 64, 0, stream>>>(sorted, cursor, A);
    k_gemm_out<<<(B_ * NSEG / 64) * (FOUT / 64), 256, 0, stream>>>(A, P, bias, out);
}

// Round 7
// 81.487 us; speedup vs baseline: 1.5511x; 1.5511x over previous
//
#include <hip/hip_runtime.h>
#include <hip/hip_bf16.h>

// Problem constants (fixed by setup_inputs)
constexpr int B_   = 4;
constexpr int C_   = 256;
constexpr int HF   = 16;
constexpr int WF   = 16;
constexpr int HH   = 512;
constexpr int WW   = 512;
constexpr int NSEG = 1024;
constexpr int FOUT = 192;
constexpr int NCELL = HF * WF;      // 256
constexpr int NPIX  = B_ * HH * WW; // 1048576
constexpr int NBINS = B_ * NSEG;    // 4096
constexpr int SB    = 512;          // sort blocks
constexpr int SBT   = 256;          // sort threads per block
constexpr int PPB   = NPIX / SB;    // 2048 pixels per block
constexpr int BPI   = SB / B_;      // 128 blocks per image
constexpr int GRP   = 32;           // sort blocks per cursor group
constexpr int NGRP  = SB / GRP;     // 16 groups (4 per image)
constexpr int GPI   = NGRP / B_;    // 4 groups per image
constexpr int CAPG  = 128;          // slot capacity per (group,bin); Poisson(64), P(>128)~0
constexpr int GPB   = 48;           // gemm_P blocks fused into k_scat

// -----------------------------------------------------------------------------
// gemm_P tiles (shares the k_scat kernel; 256-thread body)
// -----------------------------------------------------------------------------
struct PS { float Fs[32][65]; float Ws[64][33]; };

union ScatSMem {
    struct { unsigned lcnt[NSEG]; unsigned gd[NSEG]; } s;   // 8 KB
    PS p;                                                    // ~16.8 KB
};

// P[b][ij][f] = sum_c feat[b][c][ij] * w[f][c];  M=64(ij) N=64(f) K=256
__device__ void gemm_P_body(int gp, const float* __restrict__ feat,
                            const float* __restrict__ w, float* __restrict__ P,
                            PS& sm) {
    int ni = gp % 3;
    int mi = (gp / 3) & 3;
    int b  = gp / 12;
    const float* Fb = feat + (size_t)b * C_ * NCELL;

    int tid = threadIdx.x;
    int tx = tid & 15, ty = tid >> 4;
    float acc[4][4] = {};

    for (int k0 = 0; k0 < C_; k0 += 32) {
        #pragma unroll
        for (int l = 0; l < 2; ++l) {
            int li = tid * 2 + l;            // 0..511
            int kk = li >> 4;                // 0..31
            int m4 = (li & 15) * 4;
            float4 vf = *reinterpret_cast<const float4*>(&Fb[(size_t)(k0 + kk) * NCELL + mi * 64 + m4]);
            sm.Fs[kk][m4 + 0] = vf.x; sm.Fs[kk][m4 + 1] = vf.y;
            sm.Fs[kk][m4 + 2] = vf.z; sm.Fs[kk][m4 + 3] = vf.w;
            int row = li >> 3;               // 0..63
            int kq  = (li & 7) * 4;
            float4 vw = *reinterpret_cast<const float4*>(&w[(size_t)(ni * 64 + row) * C_ + k0 + kq]);
            sm.Ws[row][kq + 0] = vw.x; sm.Ws[row][kq + 1] = vw.y;
            sm.Ws[row][kq + 2] = vw.z; sm.Ws[row][kq + 3] = vw.w;
        }
        __syncthreads();
        #pragma unroll
        for (int kk = 0; kk < 32; ++kk) {
            float ar[4], wr[4];
            #pragma unroll
            for (int i = 0; i < 4; ++i) ar[i] = sm.Fs[kk][ty * 4 + i];
            #pragma unroll
            for (int j = 0; j < 4; ++j) wr[j] = sm.Ws[tx * 4 + j][kk];
            #pragma unroll
            for (int i = 0; i < 4; ++i)
                #pragma unroll
                for (int j = 0; j < 4; ++j) acc[i][j] += ar[i] * wr[j];
        }
        __syncthreads();
    }

    #pragma unroll
    for (int i = 0; i < 4; ++i)
        #pragma unroll
        for (int j = 0; j < 4; ++j)
            P[(size_t)b * NCELL * FOUT + (size_t)(mi * 64 + ty * 4 + i) * FOUT + ni * 64 + tx * 4 + j] = acc[i][j];
}

// -----------------------------------------------------------------------------
// Pass 1: blocks [0,512): minimal block-batched binning.
//   hist atomic's RETURN is the local rank -> no scan, no rank pass, no staging.
//   Reserve nonzero bins from group-sharded cursor (16 groups, ~28 RMW/counter),
//   then store each pixel coord directly to its slot. 3 barriers, 8 KB LDS.
//         blocks [512,560): gemm_P (independent, overlaps).
// -----------------------------------------------------------------------------
__global__ __launch_bounds__(256) void k_scat(const int* __restrict__ seg,
                                              float* __restrict__ segout,
                                              unsigned* __restrict__ cursor,
                                              int* __restrict__ sorted,
                                              const float* __restrict__ feat,
                                              const float* __restrict__ w,
                                              float* __restrict__ P) {
    __shared__ ScatSMem sm;
    int blk = blockIdx.x;
    if (blk >= SB) { gemm_P_body(blk - SB, feat, w, P, sm.p); return; }

    int tid = threadIdx.x;
    int q   = blk / GRP;                    // cursor group 0..15 (4 per image)

    #pragma unroll
    for (int j = 0; j < 4; ++j) sm.s.lcnt[tid * 4 + j] = 0u;
    __syncthreads();

    // phase 1: read seg (int4 x2), emit segout, LDS hist; record (s, lrank)
    size_t p0 = (size_t)blk * PPB;
    const int4* segv = reinterpret_cast<const int4*>(seg + p0);
    float4* outv = reinterpret_cast<float4*>(segout + p0);
    unsigned pr[8];
    #pragma unroll
    for (int i = 0; i < 2; ++i) {
        int4 v = segv[i * SBT + tid];
        outv[i * SBT + tid] = make_float4((float)v.x, (float)v.y,
                                          (float)v.z, (float)v.w);
        int ss[4] = { v.x, v.y, v.z, v.w };
        #pragma unroll
        for (int c = 0; c < 4; ++c) {
            unsigned s = (unsigned)ss[c];
            pr[i * 4 + c] = (s << 12) | atomicAdd(&sm.s.lcnt[s], 1u);
        }
    }
    __syncthreads();

    // phase 2: reserve runs for nonzero bins (block-batched, group-sharded)
    unsigned* curq = cursor + (size_t)q * NSEG;
    #pragma unroll
    for (int j = 0; j < 4; ++j) {
        int s = tid * 4 + j;
        unsigned c = sm.s.lcnt[s];
        if (c) sm.s.gd[s] = atomicAdd(&curq[s], c);
    }
    __syncthreads();

    // phase 3: direct slot store (independent scattered 4B writes)
    #pragma unroll
    for (int k = 0; k < 8; ++k) {
        unsigned s  = pr[k] >> 12;
        unsigned lr = pr[k] & 0xFFFu;
        unsigned r  = sm.s.gd[s] + lr;
        unsigned pix = (unsigned)((p0 + (size_t)((k >> 2) * SBT + tid) * 4 + (k & 3)) & (HH * WW - 1));
        if (r < CAPG) sorted[((size_t)q * NSEG + s) * CAPG + r] = (int)pix;
    }
}

// -----------------------------------------------------------------------------
// Pass 2: one 64-thread block per bin (b,s). Reads the bin's 4 group-runs in
// 2 full-wave rounds (lanes 0-31 -> even q, 32-63 -> odd q), int4 loads,
// 16 LDS atomics per pixel-quad, conflict-free reduce + coalesced store.
// -----------------------------------------------------------------------------
__device__ __forceinline__ void px_accum(float* acc, int p) {
    int y = p >> 9, x = p & (WW - 1);
    float sy = (y + 0.5f) * (1.0f / 32.0f) - 0.5f;
    float sx = (x + 0.5f) * (1.0f / 32.0f) - 0.5f;
    float fy = floorf(sy), fx = floorf(sx);
    int iy = (int)fy, ix = (int)fx;
    float wy1 = sy - fy, wy0 = 1.0f - wy1;
    float wx1 = sx - fx, wx0 = 1.0f - wx1;
    int y0 = max(iy, 0),          x0 = max(ix, 0);
    int y1 = min(iy + 1, HF - 1), x1 = min(ix + 1, WF - 1);
    atomicAdd(&acc[y0 * WF + x0], wy0 * wx0);
    atomicAdd(&acc[y0 * WF + x1], wy0 * wx1);
    atomicAdd(&acc[y1 * WF + x0], wy1 * wx0);
    atomicAdd(&acc[y1 * WF + x1], wy1 * wx1);
}

__global__ __launch_bounds__(64) void k_accum(const int* __restrict__ sorted,
                                              const unsigned* __restrict__ cursor,
                                              float* __restrict__ A) {
    __shared__ float acc[NCELL];
    int lane = threadIdx.x;
    int g = blockIdx.x;
    int b = g >> 10, s = g & (NSEG - 1);
    #pragma unroll
    for (int i = 0; i < 4; ++i) acc[lane + i * 64] = 0.0f;

    unsigned nq[GPI];
    #pragma unroll
    for (int j = 0; j < GPI; ++j) {
        unsigned n = cursor[(size_t)(b * GPI + j) * NSEG + s];
        nq[j] = n > CAPG ? (unsigned)CAPG : n;
    }
    __syncthreads();

    int half = lane >> 5, sub = lane & 31;
    #pragma unroll
    for (int r = 0; r < 2; ++r) {
        int j = r * 2 + half;
        int n = (int)nq[j];
        if (sub * 4 < n) {
            const int4* src4 = reinterpret_cast<const int4*>(
                sorted + ((size_t)(b * GPI + j) * NSEG + s) * CAPG);
            int4 pv = src4[sub];
            int rem = n - sub * 4;
            px_accum(acc, pv.x);
            if (rem > 1) px_accum(acc, pv.y);
            if (rem > 2) px_accum(acc, pv.z);
            if (rem > 3) px_accum(acc, pv.w);
        }
    }
    __syncthreads();

    float ntot = (float)(nq[0] + nq[1] + nq[2] + nq[3]);
    float rinv = 1.0f / fmaxf(ntot, 1.0f);
    #pragma unroll
    for (int i = 0; i < 4; ++i)
        A[(size_t)g * NCELL + lane + i * 64] = acc[lane + i * 64] * rinv;
}

// -----------------------------------------------------------------------------
// Pass 3: out[g][f] = sum_ij A[g][ij] * P[b][ij][f] + bias[f]
// M=4096 N=192 K=256. A is NT (K-contig); P is T (K-major for N).
// -----------------------------------------------------------------------------
__global__ __launch_bounds__(256) void k_gemm_out(const float* __restrict__ A,
                                                  const float* __restrict__ P,
                                                  const float* __restrict__ bias,
                                                  float* __restrict__ out) {
    int ft = blockIdx.x % 3;     // 0..2
    int st = blockIdx.x / 3;     // 0..63
    int b  = st >> 4;            // 16 seg-tiles per image

    const float* Ab = A + (size_t)st * 64 * NCELL;
    const float* Pb = P + (size_t)b * NCELL * FOUT;

    __shared__ float As[64][33];
    __shared__ float Ps[32][65];

    int tid = threadIdx.x;
    int tx = tid & 15, ty = tid >> 4;
    float acc[4][4] = {};

    for (int k0 = 0; k0 < NCELL; k0 += 32) {
        #pragma unroll
        for (int l = 0; l < 2; ++l) {
            int li = tid * 2 + l;
            int row = li >> 3;
            int kq  = (li & 7) * 4;
            float4 va = *reinterpret_cast<const float4*>(&Ab[(size_t)row * NCELL + k0 + kq]);
            As[row][kq + 0] = va.x; As[row][kq + 1] = va.y;
            As[row][kq + 2] = va.z; As[row][kq + 3] = va.w;
            int kk = li >> 4;
            int n4 = (li & 15) * 4;
            float4 vp = *reinterpret_cast<const float4*>(&Pb[(size_t)(k0 + kk) * FOUT + ft * 64 + n4]);
            Ps[kk][n4 + 0] = vp.x; Ps[kk][n4 + 1] = vp.y;
            Ps[kk][n4 + 2] = vp.z; Ps[kk][n4 + 3] = vp.w;
        }
        __syncthreads();
        #pragma unroll
        for (int kk = 0; kk < 32; ++kk) {
            float mr[4], wr[4];
            #pragma unroll
            for (int i = 0; i < 4; ++i) mr[i] = As[ty * 4 + i][kk];
            #pragma unroll
            for (int j = 0; j < 4; ++j) wr[j] = Ps[kk][tx * 4 + j];
            #pragma unroll
            for (int i = 0; i < 4; ++i)
                #pragma unroll
                for (int j = 0; j < 4; ++j) acc[i][j] += mr[i] * wr[j];
        }
        __syncthreads();
    }

    #pragma unroll
    for (int i = 0; i < 4; ++i) {
        int row = st * 64 + ty * 4 + i;
        #pragma unroll
        for (int j = 0; j < 4; ++j) {
            int f = ft * 64 + tx * 4 + j;
            out[(size_t)row * FOUT + f] = acc[i][j] + bias[f];
        }
    }
}

extern "C" void kernel_launch(void* const* d_in, const int* in_sizes, int n_in,
                              void* d_out, int out_size, void* d_ws, size_t ws_size,
                              hipStream_t stream) {
    const float* feat = (const float*)d_in[0];   // (4,256,16,16)
    const float* w    = (const float*)d_in[1];   // (192,256)
    const float* bias = (const float*)d_in[2];   // (192,)
    const int*   seg  = (const int*)d_in[3];     // (4,512,512)

    float* out    = (float*)d_out;                          // (4,1024,192)
    float* segout = out + (size_t)B_ * NSEG * FOUT;         // (4,512,512) as float

    // Workspace layout:
    char* wsb = (char*)d_ws;
    unsigned* cursor = (unsigned*)wsb;                      // 16*1024 u32 = 64 KB
    int*      sorted = (int*)(wsb + (1u << 20));            // 16*1024*128 i32 = 8 MB
    float*    A      = (float*)(wsb + (10u << 20));         // 4096*256 f32 = 4 MB
    float*    P      = (float*)(wsb + (15u << 20));         // 4*256*192 f32

    hipMemsetAsync(cursor, 0, (size_t)NGRP * NSEG * sizeof(unsigned), stream);
    k_scat    <<<SB + GPB, SBT, 0, stream>>>(seg, segout, cursor, sorted, feat, w, P);
    k_accum   <<<NBINS, 64, 0, stream>>>(sorted, cursor, A);
    k_gemm_out<<<(B_ * NSEG / 64) * (FOUT / 64), 256, 0, stream>>>(A, P, bias, out);
}

// Round 8
// 64.760 us; speedup vs baseline: 1.9518x; 1.2583x over previous
//
#include <hip/hip_runtime.h>
#include <hip/hip_bf16.h>

// Problem constants (fixed by setup_inputs)
constexpr int B_   = 4;
constexpr int C_   = 256;
constexpr int HF   = 16;
constexpr int WF   = 16;
constexpr int HH   = 512;
constexpr int WW   = 512;
constexpr int NSEG = 1024;
constexpr int FOUT = 192;
constexpr int NCELL = HF * WF;      // 256
constexpr int NPIX  = B_ * HH * WW; // 1048576
constexpr int CB    = B_ * NCELL;   // 1024 cell blocks
constexpr int GPB   = 48;           // gemm_P blocks fused into k_cell

// -----------------------------------------------------------------------------
// LDS shapes
// -----------------------------------------------------------------------------
struct PS { float Fs[32][65]; float Ws[64][33]; };          // ~16.4 KB

union CellSMem {
    struct { float lbin[NSEG]; float wr[64]; float wc[64]; } c;  // 4.5 KB
    PS p;
};

// -----------------------------------------------------------------------------
// gemm_P (256-thread body): P[b][ij][f] = sum_c feat[b][c][ij] * w[f][c]
// M=64(ij) N=64(f) K=256; 4x4 outputs per thread.
// -----------------------------------------------------------------------------
__device__ void gemm_P_body(int gp, const float* __restrict__ feat,
                            const float* __restrict__ w, float* __restrict__ P,
                            PS& sm) {
    int ni = gp % 3;
    int mi = (gp / 3) & 3;
    int b  = gp / 12;
    const float* Fb = feat + (size_t)b * C_ * NCELL;

    int tid = threadIdx.x;
    int tx = tid & 15, ty = tid >> 4;
    float acc[4][4] = {};

    for (int k0 = 0; k0 < C_; k0 += 32) {
        #pragma unroll
        for (int l = 0; l < 2; ++l) {
            int li = tid * 2 + l;            // 0..511
            int kk = li >> 4;                // 0..31
            int m4 = (li & 15) * 4;
            float4 vf = *reinterpret_cast<const float4*>(&Fb[(size_t)(k0 + kk) * NCELL + mi * 64 + m4]);
            sm.Fs[kk][m4 + 0] = vf.x; sm.Fs[kk][m4 + 1] = vf.y;
            sm.Fs[kk][m4 + 2] = vf.z; sm.Fs[kk][m4 + 3] = vf.w;
            int row = li >> 3;               // 0..63
            int kq  = (li & 7) * 4;
            float4 vw = *reinterpret_cast<const float4*>(&w[(size_t)(ni * 64 + row) * C_ + k0 + kq]);
            sm.Ws[row][kq + 0] = vw.x; sm.Ws[row][kq + 1] = vw.y;
            sm.Ws[row][kq + 2] = vw.z; sm.Ws[row][kq + 3] = vw.w;
        }
        __syncthreads();
        #pragma unroll
        for (int kk = 0; kk < 32; ++kk) {
            float ar[4], wr[4];
            #pragma unroll
            for (int i = 0; i < 4; ++i) ar[i] = sm.Fs[kk][ty * 4 + i];
            #pragma unroll
            for (int j = 0; j < 4; ++j) wr[j] = sm.Ws[tx * 4 + j][kk];
            #pragma unroll
            for (int i = 0; i < 4; ++i)
                #pragma unroll
                for (int j = 0; j < 4; ++j) acc[i][j] += ar[i] * wr[j];
        }
        __syncthreads();
    }

    #pragma unroll
    for (int i = 0; i < 4; ++i)
        #pragma unroll
        for (int j = 0; j < 4; ++j)
            P[(size_t)b * NCELL * FOUT + (size_t)(mi * 64 + ty * 4 + i) * FOUT + ni * 64 + tx * 4 + j] = acc[i][j];
}

// -----------------------------------------------------------------------------
// Pass 1: blocks [0,1024): GATHER formulation. One block per (image, cell):
//   the cell's bilinear support is a fixed 64x64 pixel window; read seg there,
//   add wr[y]*wc[x] into lbin[seg] (LDS float atomics), write one coalesced
//   AT[b][cell][0..1024) row. No global atomics / cursor / sorted array.
//   Also emits segout from a disjoint 1024-pixel chunk per block.
//         blocks [1024,1072): gemm_P (independent, overlaps).
// -----------------------------------------------------------------------------
__global__ __launch_bounds__(256) void k_cell(const int* __restrict__ seg,
                                              float* __restrict__ segout,
                                              float* __restrict__ AT,
                                              const float* __restrict__ feat,
                                              const float* __restrict__ w,
                                              float* __restrict__ P) {
    __shared__ CellSMem sm;
    int blk = blockIdx.x;
    if (blk >= CB) { gemm_P_body(blk - CB, feat, w, P, sm.p); return; }

    int tid  = threadIdx.x;
    int b    = blk >> 8;
    int cell = blk & 255;
    int cy = cell >> 4, cx = cell & 15;

    // segout passthrough (disjoint chunks, coalesced int4 -> float4)
    {
        const int4* sv = reinterpret_cast<const int4*>(seg + (size_t)blk * 1024);
        float4* ov = reinterpret_cast<float4*>(segout + (size_t)blk * 1024);
        int4 v = sv[tid];
        ov[tid] = make_float4((float)v.x, (float)v.y, (float)v.z, (float)v.w);
    }

    // zero bins; compute 1D tap-weight tables wr (rows) / wc (cols)
    #pragma unroll
    for (int j = 0; j < 4; ++j) sm.c.lbin[tid * 4 + j] = 0.0f;
    int ys = 32 * cy - 16, xs = 32 * cx - 16;
    if (tid < 128) {
        int r  = tid & 63;
        int cc = (tid < 64) ? cy : cx;
        int v  = ((tid < 64) ? ys : xs) + r;
        float wgt = 0.0f;
        if (v >= 0 && v < 512) {
            float sv = (v + 0.5f) * (1.0f / 32.0f) - 0.5f;
            float fv = floorf(sv);
            float t  = sv - fv;
            int iv = (int)fv;
            int v0 = max(iv, 0), v1 = min(iv + 1, 15);
            wgt = (v0 == cc ? 1.0f - t : 0.0f) + (v1 == cc ? t : 0.0f);
        }
        if (tid < 64) sm.c.wr[r] = wgt; else sm.c.wc[r] = wgt;
    }
    __syncthreads();

    // gather over the 64x64 support window: 4 rounds of 16 rows x 16 int4
    const int* srow = seg + (size_t)b * (HH * WW);
    int rr = tid >> 4;                // 0..15
    int cg = (tid & 15) * 4;          // 0,4,...,60
    #pragma unroll
    for (int rnd = 0; rnd < 4; ++rnd) {
        int r = rnd * 16 + rr;
        int y = ys + r;
        int x0 = xs + cg;
        if (y >= 0 && y < HH && x0 >= 0 && x0 + 3 < WW) {
            float wy = sm.c.wr[r];
            if (wy > 0.0f) {
                int4 v = *reinterpret_cast<const int4*>(srow + (size_t)y * WW + x0);
                float w0 = wy * sm.c.wc[cg + 0];
                float w1 = wy * sm.c.wc[cg + 1];
                float w2 = wy * sm.c.wc[cg + 2];
                float w3 = wy * sm.c.wc[cg + 3];
                if (w0 > 0.0f) atomicAdd(&sm.c.lbin[v.x], w0);
                if (w1 > 0.0f) atomicAdd(&sm.c.lbin[v.y], w1);
                if (w2 > 0.0f) atomicAdd(&sm.c.lbin[v.z], w2);
                if (w3 > 0.0f) atomicAdd(&sm.c.lbin[v.w], w3);
            }
        }
    }
    __syncthreads();

    // coalesced row store: AT[b][cell][s]
    float4* dst = reinterpret_cast<float4*>(AT + ((size_t)(b * NCELL + cell)) * NSEG);
    dst[tid] = make_float4(sm.c.lbin[tid * 4 + 0], sm.c.lbin[tid * 4 + 1],
                           sm.c.lbin[tid * 4 + 2], sm.c.lbin[tid * 4 + 3]);
}

// -----------------------------------------------------------------------------
// Pass 2: out[s][f] = (sum_k AT[b][k][s] * P[b][k][f]) / max(cnt[s],1) + bias[f]
// where cnt[s] = sum_k AT[b][k][s] is accumulated from the same LDS reads.
// M=1024(s)/image, N=192(f), K=256(cells). Both operands K-major.
// -----------------------------------------------------------------------------
__global__ __launch_bounds__(256) void k_gemm_out(const float* __restrict__ AT,
                                                  const float* __restrict__ P,
                                                  const float* __restrict__ bias,
                                                  float* __restrict__ out) {
    int ft = blockIdx.x % 3;     // 0..2
    int st = blockIdx.x / 3;     // 0..63
    int b  = st >> 4;
    int s0 = (st & 15) * 64;

    const float* ATb = AT + (size_t)b * NCELL * NSEG;
    const float* Pb  = P  + (size_t)b * NCELL * FOUT;

    __shared__ float As[32][65];
    __shared__ float Ps[32][65];

    int tid = threadIdx.x;
    int tx = tid & 15, ty = tid >> 4;
    float acc[4][4] = {};
    float cnt[4] = {};

    for (int k0 = 0; k0 < NCELL; k0 += 32) {
        #pragma unroll
        for (int l = 0; l < 2; ++l) {
            int li = tid * 2 + l;            // 0..511
            int kk = li >> 4;                // 0..31
            int e4 = (li & 15) * 4;
            float4 va = *reinterpret_cast<const float4*>(&ATb[(size_t)(k0 + kk) * NSEG + s0 + e4]);
            As[kk][e4 + 0] = va.x; As[kk][e4 + 1] = va.y;
            As[kk][e4 + 2] = va.z; As[kk][e4 + 3] = va.w;
            float4 vp = *reinterpret_cast<const float4*>(&Pb[(size_t)(k0 + kk) * FOUT + ft * 64 + e4]);
            Ps[kk][e4 + 0] = vp.x; Ps[kk][e4 + 1] = vp.y;
            Ps[kk][e4 + 2] = vp.z; Ps[kk][e4 + 3] = vp.w;
        }
        __syncthreads();
        #pragma unroll
        for (int kk = 0; kk < 32; ++kk) {
            float ar[4], wr[4];
            #pragma unroll
            for (int i = 0; i < 4; ++i) { ar[i] = As[kk][ty * 4 + i]; cnt[i] += ar[i]; }
            #pragma unroll
            for (int j = 0; j < 4; ++j) wr[j] = Ps[kk][tx * 4 + j];
            #pragma unroll
            for (int i = 0; i < 4; ++i)
                #pragma unroll
                for (int j = 0; j < 4; ++j) acc[i][j] += ar[i] * wr[j];
        }
        __syncthreads();
    }

    #pragma unroll
    for (int i = 0; i < 4; ++i) {
        int row = st * 64 + ty * 4 + i;      // == b*NSEG + s0 + ty*4 + i
        float rinv = 1.0f / fmaxf(cnt[i], 1.0f);
        #pragma unroll
        for (int j = 0; j < 4; ++j) {
            int f = ft * 64 + tx * 4 + j;
            out[(size_t)row * FOUT + f] = acc[i][j] * rinv + bias[f];
        }
    }
}

extern "C" void kernel_launch(void* const* d_in, const int* in_sizes, int n_in,
                              void* d_out, int out_size, void* d_ws, size_t ws_size,
                              hipStream_t stream) {
    const float* feat = (const float*)d_in[0];   // (4,256,16,16)
    const float* w    = (const float*)d_in[1];   // (192,256)
    const float* bias = (const float*)d_in[2];   // (192,)
    const int*   seg  = (const int*)d_in[3];     // (4,512,512)

    float* out    = (float*)d_out;                          // (4,1024,192)
    float* segout = out + (size_t)B_ * NSEG * FOUT;         // (4,512,512) as float

    // Workspace layout:
    char* wsb = (char*)d_ws;
    float* AT = (float*)wsb;                                // 4*256*1024 f32 = 4 MB
    float* P  = (float*)(wsb + (5u << 20));                 // 4*256*192 f32

    k_cell    <<<CB + GPB, 256, 0, stream>>>(seg, segout, AT, feat, w, P);
    k_gemm_out<<<(B_ * NSEG / 64) * (FOUT / 64), 256, 0, stream>>>(AT, P, bias, out);
}

// Round 9
// 49.027 us; speedup vs baseline: 2.5781x; 1.3209x over previous
//
#include <hip/hip_runtime.h>
#include <hip/hip_bf16.h>

// Problem constants (fixed by setup_inputs)
constexpr int B_   = 4;
constexpr int C_   = 256;
constexpr int HF   = 16;
constexpr int WF   = 16;
constexpr int HH   = 512;
constexpr int WW   = 512;
constexpr int NSEG = 1024;
constexpr int FOUT = 192;
constexpr int NCELL = HF * WF;      // 256
constexpr int CB    = B_ * NCELL;   // 1024 cell blocks
constexpr int GPB   = 48;           // gemm_P blocks fused into k_cell

// -----------------------------------------------------------------------------
// LDS shapes
// -----------------------------------------------------------------------------
struct PS { float Fs[32][65]; float Ws[64][33]; };          // ~16.6 KB

union CellSMem {
    struct { unsigned lbin[NSEG]; unsigned wr[64]; unsigned wc[64]; } c; // 4.5 KB
    PS p;
};

// -----------------------------------------------------------------------------
// gemm_P (256-thread body): P[b][ij][f] = sum_c feat[b][c][ij] * w[f][c]
// M=64(ij) N=64(f) K=256; 4x4 outputs per thread.
// -----------------------------------------------------------------------------
__device__ void gemm_P_body(int gp, const float* __restrict__ feat,
                            const float* __restrict__ w, float* __restrict__ P,
                            PS& sm) {
    int ni = gp % 3;
    int mi = (gp / 3) & 3;
    int b  = gp / 12;
    const float* Fb = feat + (size_t)b * C_ * NCELL;

    int tid = threadIdx.x;
    int tx = tid & 15, ty = tid >> 4;
    float acc[4][4] = {};

    for (int k0 = 0; k0 < C_; k0 += 32) {
        #pragma unroll
        for (int l = 0; l < 2; ++l) {
            int li = tid * 2 + l;            // 0..511
            int kk = li >> 4;                // 0..31
            int m4 = (li & 15) * 4;
            float4 vf = *reinterpret_cast<const float4*>(&Fb[(size_t)(k0 + kk) * NCELL + mi * 64 + m4]);
            sm.Fs[kk][m4 + 0] = vf.x; sm.Fs[kk][m4 + 1] = vf.y;
            sm.Fs[kk][m4 + 2] = vf.z; sm.Fs[kk][m4 + 3] = vf.w;
            int row = li >> 3;               // 0..63
            int kq  = (li & 7) * 4;
            float4 vw = *reinterpret_cast<const float4*>(&w[(size_t)(ni * 64 + row) * C_ + k0 + kq]);
            sm.Ws[row][kq + 0] = vw.x; sm.Ws[row][kq + 1] = vw.y;
            sm.Ws[row][kq + 2] = vw.z; sm.Ws[row][kq + 3] = vw.w;
        }
        __syncthreads();
        #pragma unroll
        for (int kk = 0; kk < 32; ++kk) {
            float ar[4], wr[4];
            #pragma unroll
            for (int i = 0; i < 4; ++i) ar[i] = sm.Fs[kk][ty * 4 + i];
            #pragma unroll
            for (int j = 0; j < 4; ++j) wr[j] = sm.Ws[tx * 4 + j][kk];
            #pragma unroll
            for (int i = 0; i < 4; ++i)
                #pragma unroll
                for (int j = 0; j < 4; ++j) acc[i][j] += ar[i] * wr[j];
        }
        __syncthreads();
    }

    #pragma unroll
    for (int i = 0; i < 4; ++i)
        #pragma unroll
        for (int j = 0; j < 4; ++j)
            P[(size_t)b * NCELL * FOUT + (size_t)(mi * 64 + ty * 4 + i) * FOUT + ni * 64 + tx * 4 + j] = acc[i][j];
}

// -----------------------------------------------------------------------------
// Pass 1: blocks [0,1024): GATHER, fixed-point. One block per (image, cell):
//   64x64 support window; weight of pixel (y,x) toward this cell is
//   wr[y]*wc[x] / 4096 with wr,wc integer in [0,64] (exact dyadics).
//   Accumulate wr*wc into lbin[seg] via native uint LDS atomics
//   (fire-and-forget ds_add_u32 -- no CAS loop, no dependency chain),
//   then store AT row as float * (1/4096)  (exact: sums < 2^24).
//         blocks [1024,1072): gemm_P (independent, overlaps).
// -----------------------------------------------------------------------------
__global__ __launch_bounds__(256) void k_cell(const int* __restrict__ seg,
                                              float* __restrict__ segout,
                                              float* __restrict__ AT,
                                              const float* __restrict__ feat,
                                              const float* __restrict__ w,
                                              float* __restrict__ P) {
    __shared__ CellSMem sm;
    int blk = blockIdx.x;
    if (blk >= CB) { gemm_P_body(blk - CB, feat, w, P, sm.p); return; }

    int tid  = threadIdx.x;
    int b    = blk >> 8;
    int cell = blk & 255;
    int cy = cell >> 4, cx = cell & 15;

    // segout passthrough (disjoint chunks, coalesced int4 -> float4)
    {
        const int4* sv = reinterpret_cast<const int4*>(seg + (size_t)blk * 1024);
        float4* ov = reinterpret_cast<float4*>(segout + (size_t)blk * 1024);
        int4 v = sv[tid];
        ov[tid] = make_float4((float)v.x, (float)v.y, (float)v.z, (float)v.w);
    }

    // zero bins; integer 1D tap-weight tables wr (rows) / wc (cols), in 1/64ths
    #pragma unroll
    for (int j = 0; j < 4; ++j) sm.c.lbin[tid * 4 + j] = 0u;
    int ys = 32 * cy - 16, xs = 32 * cx - 16;
    if (tid < 128) {
        int r  = tid & 63;
        int cc = (tid < 64) ? cy : cx;
        int v  = ((tid < 64) ? ys : xs) + r;
        unsigned wgt = 0u;
        if (v >= 0 && v < 512) {
            int twov = 2 * v - 31;                 // src*64 = (2v-31)... /64
            int num  = ((twov % 64) + 64) % 64;    // frac in 1/64ths (exact)
            int iv   = (twov - num) >> 6;          // floor
            int v0 = max(iv, 0), v1 = min(iv + 1, 15);
            wgt = (unsigned)((v0 == cc ? 64 - num : 0) + (v1 == cc ? num : 0));
        }
        if (tid < 64) sm.c.wr[r] = wgt; else sm.c.wc[r] = wgt;
    }
    __syncthreads();

    // hoist this thread's 4 column weights (fixed across rounds)
    int rr = tid >> 4;                // 0..15
    int cg = (tid & 15) * 4;          // 0,4,...,60
    unsigned wc0 = sm.c.wc[cg + 0], wc1 = sm.c.wc[cg + 1];
    unsigned wc2 = sm.c.wc[cg + 2], wc3 = sm.c.wc[cg + 3];

    // gather over the 64x64 support window: 4 rounds of 16 rows x 16 int4
    const int* srow = seg + (size_t)b * (HH * WW);
    #pragma unroll
    for (int rnd = 0; rnd < 4; ++rnd) {
        int r = rnd * 16 + rr;
        int y = ys + r;
        int x0 = xs + cg;
        if (y >= 0 && y < HH && x0 >= 0 && x0 + 3 < WW) {
            unsigned wy = sm.c.wr[r];
            if (wy) {
                int4 v = *reinterpret_cast<const int4*>(srow + (size_t)y * WW + x0);
                atomicAdd(&sm.c.lbin[v.x], wy * wc0);
                atomicAdd(&sm.c.lbin[v.y], wy * wc1);
                atomicAdd(&sm.c.lbin[v.z], wy * wc2);
                atomicAdd(&sm.c.lbin[v.w], wy * wc3);
            }
        }
    }
    __syncthreads();

    // coalesced row store: AT[b][cell][s] = lbin[s] / 4096  (exact)
    float4* dst = reinterpret_cast<float4*>(AT + ((size_t)(b * NCELL + cell)) * NSEG);
    constexpr float SCL = 1.0f / 4096.0f;
    dst[tid] = make_float4(sm.c.lbin[tid * 4 + 0] * SCL, sm.c.lbin[tid * 4 + 1] * SCL,
                           sm.c.lbin[tid * 4 + 2] * SCL, sm.c.lbin[tid * 4 + 3] * SCL);
}

// -----------------------------------------------------------------------------
// Pass 2: out[s][f] = (sum_k AT[b][k][s] * P[b][k][f]) / max(cnt[s],1) + bias[f]
// where cnt[s] = sum_k AT[b][k][s] is accumulated from the same LDS reads.
// M=1024(s)/image, N=192(f), K=256(cells). Both operands K-major.
// -----------------------------------------------------------------------------
__global__ __launch_bounds__(256) void k_gemm_out(const float* __restrict__ AT,
                                                  const float* __restrict__ P,
                                                  const float* __restrict__ bias,
                                                  float* __restrict__ out) {
    int ft = blockIdx.x % 3;     // 0..2
    int st = blockIdx.x / 3;     // 0..63
    int b  = st >> 4;
    int s0 = (st & 15) * 64;

    const float* ATb = AT + (size_t)b * NCELL * NSEG;
    const float* Pb  = P  + (size_t)b * NCELL * FOUT;

    __shared__ float As[32][65];
    __shared__ float Ps[32][65];

    int tid = threadIdx.x;
    int tx = tid & 15, ty = tid >> 4;
    float acc[4][4] = {};
    float cnt[4] = {};

    for (int k0 = 0; k0 < NCELL; k0 += 32) {
        #pragma unroll
        for (int l = 0; l < 2; ++l) {
            int li = tid * 2 + l;            // 0..511
            int kk = li >> 4;                // 0..31
            int e4 = (li & 15) * 4;
            float4 va = *reinterpret_cast<const float4*>(&ATb[(size_t)(k0 + kk) * NSEG + s0 + e4]);
            As[kk][e4 + 0] = va.x; As[kk][e4 + 1] = va.y;
            As[kk][e4 + 2] = va.z; As[kk][e4 + 3] = va.w;
            float4 vp = *reinterpret_cast<const float4*>(&Pb[(size_t)(k0 + kk) * FOUT + ft * 64 + e4]);
            Ps[kk][e4 + 0] = vp.x; Ps[kk][e4 + 1] = vp.y;
            Ps[kk][e4 + 2] = vp.z; Ps[kk][e4 + 3] = vp.w;
        }
        __syncthreads();
        #pragma unroll
        for (int kk = 0; kk < 32; ++kk) {
            float ar[4], wr[4];
            #pragma unroll
            for (int i = 0; i < 4; ++i) { ar[i] = As[kk][ty * 4 + i]; cnt[i] += ar[i]; }
            #pragma unroll
            for (int j = 0; j < 4; ++j) wr[j] = Ps[kk][tx * 4 + j];
            #pragma unroll
            for (int i = 0; i < 4; ++i)
                #pragma unroll
                for (int j = 0; j < 4; ++j) acc[i][j] += ar[i] * wr[j];
        }
        __syncthreads();
    }

    #pragma unroll
    for (int i = 0; i < 4; ++i) {
        int row = st * 64 + ty * 4 + i;      // == b*NSEG + s0 + ty*4 + i
        float rinv = 1.0f / fmaxf(cnt[i], 1.0f);
        #pragma unroll
        for (int j = 0; j < 4; ++j) {
            int f = ft * 64 + tx * 4 + j;
            out[(size_t)row * FOUT + f] = acc[i][j] * rinv + bias[f];
        }
    }
}

extern "C" void kernel_launch(void* const* d_in, const int* in_sizes, int n_in,
                              void* d_out, int out_size, void* d_ws, size_t ws_size,
                              hipStream_t stream) {
    const float* feat = (const float*)d_in[0];   // (4,256,16,16)
    const float* w    = (const float*)d_in[1];   // (192,256)
    const float* bias = (const float*)d_in[2];   // (192,)
    const int*   seg  = (const int*)d_in[3];     // (4,512,512)

    float* out    = (float*)d_out;                          // (4,1024,192)
    float* segout = out + (size_t)B_ * NSEG * FOUT;         // (4,512,512) as float

    // Workspace layout:
    char* wsb = (char*)d_ws;
    float* AT = (float*)wsb;                                // 4*256*1024 f32 = 4 MB
    float* P  = (float*)(wsb + (5u << 20));                 // 4*256*192 f32

    k_cell    <<<CB + GPB, 256, 0, stream>>>(seg, segout, AT, feat, w, P);
    k_gemm_out<<<(B_ * NSEG / 64) * (FOUT / 64), 256, 0, stream>>>(AT, P, bias, out);
}

// Round 10
// 48.502 us; speedup vs baseline: 2.6060x; 1.0108x over previous
//
#include <hip/hip_runtime.h>
#include <hip/hip_bf16.h>

// Problem constants (fixed by setup_inputs)
constexpr int B_   = 4;
constexpr int C_   = 256;
constexpr int HF   = 16;
constexpr int WF   = 16;
constexpr int HH   = 512;
constexpr int WW   = 512;
constexpr int NSEG = 1024;
constexpr int FOUT = 192;
constexpr int NCELL = HF * WF;      // 256
constexpr int CB    = B_ * NCELL;   // 1024 cell blocks
constexpr int GPB   = 48;           // gemm_P blocks (FIRST in grid)

// -----------------------------------------------------------------------------
// LDS shapes
// -----------------------------------------------------------------------------
struct PS { float Fs[32][65]; float Ws[64][33]; };          // ~16.6 KB

union CellSMem {
    struct { unsigned lbin[NSEG]; unsigned wc[64]; } c;     // 4.25 KB
    PS p;
};

// -----------------------------------------------------------------------------
// gemm_P (256-thread body): P[b][ij][f] = sum_c feat[b][c][ij] * w[f][c]
// M=64(ij) N=64(f) K=256; 4x4 outputs per thread.
// -----------------------------------------------------------------------------
__device__ void gemm_P_body(int gp, const float* __restrict__ feat,
                            const float* __restrict__ w, float* __restrict__ P,
                            PS& sm) {
    int ni = gp % 3;
    int mi = (gp / 3) & 3;
    int b  = gp / 12;
    const float* Fb = feat + (size_t)b * C_ * NCELL;

    int tid = threadIdx.x;
    int tx = tid & 15, ty = tid >> 4;
    float acc[4][4] = {};

    for (int k0 = 0; k0 < C_; k0 += 32) {
        #pragma unroll
        for (int l = 0; l < 2; ++l) {
            int li = tid * 2 + l;            // 0..511
            int kk = li >> 4;                // 0..31
            int m4 = (li & 15) * 4;
            float4 vf = *reinterpret_cast<const float4*>(&Fb[(size_t)(k0 + kk) * NCELL + mi * 64 + m4]);
            sm.Fs[kk][m4 + 0] = vf.x; sm.Fs[kk][m4 + 1] = vf.y;
            sm.Fs[kk][m4 + 2] = vf.z; sm.Fs[kk][m4 + 3] = vf.w;
            int row = li >> 3;               // 0..63
            int kq  = (li & 7) * 4;
            float4 vw = *reinterpret_cast<const float4*>(&w[(size_t)(ni * 64 + row) * C_ + k0 + kq]);
            sm.Ws[row][kq + 0] = vw.x; sm.Ws[row][kq + 1] = vw.y;
            sm.Ws[row][kq + 2] = vw.z; sm.Ws[row][kq + 3] = vw.w;
        }
        __syncthreads();
        #pragma unroll
        for (int kk = 0; kk < 32; ++kk) {
            float ar[4], wr[4];
            #pragma unroll
            for (int i = 0; i < 4; ++i) ar[i] = sm.Fs[kk][ty * 4 + i];
            #pragma unroll
            for (int j = 0; j < 4; ++j) wr[j] = sm.Ws[tx * 4 + j][kk];
            #pragma unroll
            for (int i = 0; i < 4; ++i)
                #pragma unroll
                for (int j = 0; j < 4; ++j) acc[i][j] += ar[i] * wr[j];
        }
        __syncthreads();
    }

    #pragma unroll
    for (int i = 0; i < 4; ++i)
        #pragma unroll
        for (int j = 0; j < 4; ++j)
            P[(size_t)b * NCELL * FOUT + (size_t)(mi * 64 + ty * 4 + i) * FOUT + ni * 64 + tx * 4 + j] = acc[i][j];
}

// -----------------------------------------------------------------------------
// 1D tap weight of coordinate v (pixel) toward cell index cc, in 1/64ths.
// Exact integer arithmetic; OOB v handled by caller (returns 0).
// -----------------------------------------------------------------------------
__device__ __forceinline__ unsigned tapw(int v, int cc) {
    if (v < 0 || v >= 512) return 0u;
    int twov = 2 * v - 31;                 // src*64 = (2v-31)*? ... exact /64
    int num  = ((twov % 64) + 64) % 64;    // frac in 1/64ths
    int iv   = (twov - num) >> 6;          // floor
    int v0 = max(iv, 0), v1 = min(iv + 1, 15);
    return (unsigned)((v0 == cc ? 64 - num : 0) + (v1 == cc ? num : 0));
}

// -----------------------------------------------------------------------------
// Pass 1: blocks [0,48): gemm_P (launched FIRST so it overlaps the cells).
//         blocks [48,1072): GATHER, fixed-point. One block per (image, cell):
//   64x64 support window. Thread t owns row r=t>>2, 16 px at col (t&3)*16:
//   4 unconditional clamped int4 loads (issued before the barrier, full MLP),
//   row-weight in registers, col-weights via 4 uint4 LDS reads, then 16
//   fire-and-forget ds_add_u32. AT row stored as float/4096 (exact).
// -----------------------------------------------------------------------------
__global__ __launch_bounds__(256) void k_cell(const int* __restrict__ seg,
                                              float* __restrict__ segout,
                                              float* __restrict__ AT,
                                              const float* __restrict__ feat,
                                              const float* __restrict__ w,
                                              float* __restrict__ P) {
    __shared__ CellSMem sm;
    int blk = blockIdx.x;
    if (blk < GPB) { gemm_P_body(blk, feat, w, P, sm.p); return; }

    int cb   = blk - GPB;
    int tid  = threadIdx.x;
    int b    = cb >> 8;
    int cell = cb & 255;
    int cy = cell >> 4, cx = cell & 15;
    int ys = 32 * cy - 16, xs = 32 * cx - 16;

    // segout passthrough load (independent; store later)
    const int4* sv = reinterpret_cast<const int4*>(seg + (size_t)cb * 1024);
    float4*     ov = reinterpret_cast<float4*>(segout + (size_t)cb * 1024);
    int4 pv = sv[tid];

    // zero bins; wc table (u32 weights, window cols 0..63)
    #pragma unroll
    for (int j = 0; j < 4; ++j) sm.c.lbin[tid * 4 + j] = 0u;
    if (tid < 64) sm.c.wc[tid] = tapw(xs + tid, cx);

    // per-thread row weight in regs; 4 clamped unconditional int4 loads
    int r  = tid >> 2;                 // window row 0..63
    int y  = ys + r;
    unsigned wrv = tapw(y, cy);
    int yc = min(max(y, 0), HH - 1);
    int cg = (tid & 3) * 16;           // window col of first pixel
    int x0 = xs + cg;
    int xc = min(max(x0, 0), WW - 16); // 16 px fit, 16B-aligned (mult of 16)

    const int4* lrow = reinterpret_cast<const int4*>(seg + (size_t)b * (HH * WW) + (size_t)yc * WW + xc);
    int4 v0 = lrow[0], v1 = lrow[1], v2 = lrow[2], v3 = lrow[3];

    ov[tid] = make_float4((float)pv.x, (float)pv.y, (float)pv.z, (float)pv.w);
    __syncthreads();

    // col weights (vector LDS reads), then 16 back-to-back atomics
    uint4 wa = *reinterpret_cast<const uint4*>(&sm.c.wc[cg + 0]);
    uint4 wb = *reinterpret_cast<const uint4*>(&sm.c.wc[cg + 4]);
    uint4 wcv = *reinterpret_cast<const uint4*>(&sm.c.wc[cg + 8]);
    uint4 wd = *reinterpret_cast<const uint4*>(&sm.c.wc[cg + 12]);

    atomicAdd(&sm.c.lbin[v0.x], wrv * wa.x);
    atomicAdd(&sm.c.lbin[v0.y], wrv * wa.y);
    atomicAdd(&sm.c.lbin[v0.z], wrv * wa.z);
    atomicAdd(&sm.c.lbin[v0.w], wrv * wa.w);
    atomicAdd(&sm.c.lbin[v1.x], wrv * wb.x);
    atomicAdd(&sm.c.lbin[v1.y], wrv * wb.y);
    atomicAdd(&sm.c.lbin[v1.z], wrv * wb.z);
    atomicAdd(&sm.c.lbin[v1.w], wrv * wb.w);
    atomicAdd(&sm.c.lbin[v2.x], wrv * wcv.x);
    atomicAdd(&sm.c.lbin[v2.y], wrv * wcv.y);
    atomicAdd(&sm.c.lbin[v2.z], wrv * wcv.z);
    atomicAdd(&sm.c.lbin[v2.w], wrv * wcv.w);
    atomicAdd(&sm.c.lbin[v3.x], wrv * wd.x);
    atomicAdd(&sm.c.lbin[v3.y], wrv * wd.y);
    atomicAdd(&sm.c.lbin[v3.z], wrv * wd.z);
    atomicAdd(&sm.c.lbin[v3.w], wrv * wd.w);
    __syncthreads();

    // coalesced row store: AT[b][cell][s] = lbin[s] / 4096  (exact)
    float4* dst = reinterpret_cast<float4*>(AT + ((size_t)(b * NCELL + cell)) * NSEG);
    constexpr float SCL = 1.0f / 4096.0f;
    dst[tid] = make_float4(sm.c.lbin[tid * 4 + 0] * SCL, sm.c.lbin[tid * 4 + 1] * SCL,
                           sm.c.lbin[tid * 4 + 2] * SCL, sm.c.lbin[tid * 4 + 3] * SCL);
}

// -----------------------------------------------------------------------------
// Pass 2: out[s][f] = (sum_k AT[b][k][s] * P[b][k][f]) / max(cnt[s],1) + bias[f]
// cnt fused from the same LDS reads. M-tile 32 (384 blocks, 2x parallelism of
// the old 64-tile version), N=64(f), K=256(cells). Both operands K-major.
// -----------------------------------------------------------------------------
__global__ __launch_bounds__(256) void k_gemm_out(const float* __restrict__ AT,
                                                  const float* __restrict__ P,
                                                  const float* __restrict__ bias,
                                                  float* __restrict__ out) {
    int ft = blockIdx.x % 3;     // 0..2
    int st = blockIdx.x / 3;     // 0..127
    int b  = st >> 5;
    int s0 = (st & 31) * 32;

    const float* ATb = AT + (size_t)b * NCELL * NSEG;
    const float* Pb  = P  + (size_t)b * NCELL * FOUT;

    __shared__ float As[32][33];
    __shared__ float Ps[32][65];

    int tid = threadIdx.x;
    int tx = tid & 15, ty = tid >> 4;
    float acc[2][4] = {};
    float cnt[2] = {};

    for (int k0 = 0; k0 < NCELL; k0 += 32) {
        {
            int kk = tid >> 3, e4 = (tid & 7) * 4;       // A: 1 float4/thread
            float4 va = *reinterpret_cast<const float4*>(&ATb[(size_t)(k0 + kk) * NSEG + s0 + e4]);
            As[kk][e4 + 0] = va.x; As[kk][e4 + 1] = va.y;
            As[kk][e4 + 2] = va.z; As[kk][e4 + 3] = va.w;
            #pragma unroll
            for (int l = 0; l < 2; ++l) {                // P: 2 float4/thread
                int li = tid * 2 + l;
                int kp = li >> 4, e = (li & 15) * 4;
                float4 vp = *reinterpret_cast<const float4*>(&Pb[(size_t)(k0 + kp) * FOUT + ft * 64 + e]);
                Ps[kp][e + 0] = vp.x; Ps[kp][e + 1] = vp.y;
                Ps[kp][e + 2] = vp.z; Ps[kp][e + 3] = vp.w;
            }
        }
        __syncthreads();
        #pragma unroll
        for (int kk = 0; kk < 32; ++kk) {
            float ar[2], wr[4];
            #pragma unroll
            for (int i = 0; i < 2; ++i) { ar[i] = As[kk][ty * 2 + i]; cnt[i] += ar[i]; }
            #pragma unroll
            for (int j = 0; j < 4; ++j) wr[j] = Ps[kk][tx * 4 + j];
            #pragma unroll
            for (int i = 0; i < 2; ++i)
                #pragma unroll
                for (int j = 0; j < 4; ++j) acc[i][j] += ar[i] * wr[j];
        }
        __syncthreads();
    }

    #pragma unroll
    for (int i = 0; i < 2; ++i) {
        int row = b * NSEG + s0 + ty * 2 + i;
        float rinv = 1.0f / fmaxf(cnt[i], 1.0f);
        #pragma unroll
        for (int j = 0; j < 4; ++j) {
            int f = ft * 64 + tx * 4 + j;
            out[(size_t)row * FOUT + f] = acc[i][j] * rinv + bias[f];
        }
    }
}

extern "C" void kernel_launch(void* const* d_in, const int* in_sizes, int n_in,
                              void* d_out, int out_size, void* d_ws, size_t ws_size,
                              hipStream_t stream) {
    const float* feat = (const float*)d_in[0];   // (4,256,16,16)
    const float* w    = (const float*)d_in[1];   // (192,256)
    const float* bias = (const float*)d_in[2];   // (192,)
    const int*   seg  = (const int*)d_in[3];     // (4,512,512)

    float* out    = (float*)d_out;                          // (4,1024,192)
    float* segout = out + (size_t)B_ * NSEG * FOUT;         // (4,512,512) as float

    // Workspace layout:
    char* wsb = (char*)d_ws;
    float* AT = (float*)wsb;                                // 4*256*1024 f32 = 4 MB
    float* P  = (float*)(wsb + (5u << 20));                 // 4*256*192 f32

    k_cell    <<<GPB + CB, 256, 0, stream>>>(seg, segout, AT, feat, w, P);
    k_gemm_out<<<(B_ * NSEG / 32) * (FOUT / 64), 256, 0, stream>>>(AT, P, bias, out);
}